// Round 6
// baseline (1003.452 us; speedup 1.0000x reference)
//
#include <hip/hip_runtime.h>
#include <hip/hip_bf16.h>
#include <math.h>

#define NN 100000
#define NNP 100096          // padded to 782*128
#define NE 300000
#define HID 128
#define EMB 64
#define NG 4096
#define DEG_CAP 32
#define XS 512              // X row stride in elements

typedef __bf16 bf16x8 __attribute__((ext_vector_type(8)));
typedef float  f32x16 __attribute__((ext_vector_type(16)));
typedef short  short8 __attribute__((ext_vector_type(8)));

typedef const __attribute__((address_space(1))) unsigned int* gas_u32;
typedef __attribute__((address_space(3))) unsigned int* las_u32;

__device__ __forceinline__ void gload16(const void* g, void* l) {
    // async global->LDS DMA, 16B/lane; LDS dest = wave-uniform base + lane*16
    __builtin_amdgcn_global_load_lds((gas_u32)g, (las_u32)l, 16, 0, 0);
}

__device__ __forceinline__ float bf2f(unsigned short u) {
    unsigned int x = ((unsigned int)u) << 16;
    return __builtin_bit_cast(float, x);
}
__device__ __forceinline__ unsigned short f2bf(float f) {
    unsigned int x = __builtin_bit_cast(unsigned int, f);
    unsigned int r = x + 0x7fff + ((x >> 16) & 1);
    return (unsigned short)(r >> 16);
}
__device__ __forceinline__ float sigm(float x) { return 1.f / (1.f + __expf(-x)); }

// ---------------------------------------------------------------------------
// h init: node_features f32 -> Y bf16 [NNP][128]; pad rows zeroed.
// ---------------------------------------------------------------------------
__global__ __launch_bounds__(256) void k_init(const float* __restrict__ nf,
                                              unsigned short* __restrict__ Y) {
    int id = blockIdx.x * 256 + threadIdx.x;   // NNP*HID
    int n = id >> 7, c = id & 127;
    Y[(long)n * HID + c] = (n < NN) ? f2bf(nf[(long)n * HID + c]) : (unsigned short)0;
}

// ---------------------------------------------------------------------------
// CSR build (deg true counts; csr capped at DEG_CAP)
// ---------------------------------------------------------------------------
__global__ __launch_bounds__(256) void k_build_csr(const int* __restrict__ ei,
                                                   int* __restrict__ deg,
                                                   int* __restrict__ csr) {
    int id = blockIdx.x * 256 + threadIdx.x;
    if (id >= 3 * NE) return;
    int t = id / NE;
    int i = id - t * NE;
    int src = ei[(t * 2 + 0) * NE + i];
    int dst = ei[(t * 2 + 1) * NE + i];
    int p = atomicAdd(&deg[t * NN + dst], 1);
    if (p < DEG_CAP) csr[((long)t * NN + dst) * DEG_CAP + p] = src;
}

__global__ __launch_bounds__(256) void k_pack_deg(const int* __restrict__ deg,
                                                  int4* __restrict__ degp) {
    int n = blockIdx.x * 256 + threadIdx.x;
    if (n >= NNP) return;
    int4 v; v.x = 0; v.y = 0; v.z = 0; v.w = 0;
    if (n < NN) { v.x = deg[n]; v.y = deg[NN + n]; v.z = deg[2 * NN + n]; }
    degp[n] = v;
}

// ---------------------------------------------------------------------------
// Wnk[n'][k] bf16 with PERMUTED N: n' = c*4 + sec (sec-minor), so each
// 128-col block owns 32 complete channels (all 4 gate sections).
// K layout: k<384 -> A_cat (Wm @ Wih_sec^T), k>=384 -> h (Whh_sec).
// sec: 0=r, 1=z, 2=In(i-only), 3=Hn(h-only).
// ---------------------------------------------------------------------------
__global__ __launch_bounds__(512) void k_build_w(const float* __restrict__ Wmsg,
                                                 const float* __restrict__ Wih,
                                                 const float* __restrict__ Whh,
                                                 unsigned short* __restrict__ Wnk) {
    int np = blockIdx.x;       // 0..511 permuted col
    int k = threadIdx.x;       // 0..511
    int c = np >> 2, sec = np & 3;
    float v = 0.f;
    if (k < 384) {
        if (sec < 3) {
            int t = k >> 7, kk = k & 127;
            const float* wm = Wmsg + ((long)t * HID + kk) * HID;
            const float* wi = Wih + (long)(sec * HID + c) * HID;
            float s = 0.f;
            for (int j = 0; j < HID; j++) s += wm[j] * wi[j];
            v = s;
        }
    } else {
        int kk = k - 384;
        if (sec == 0)      v = Whh[(long)c * HID + kk];
        else if (sec == 1) v = Whh[(long)(HID + c) * HID + kk];
        else if (sec == 3) v = Whh[(long)(2 * HID + c) * HID + kk];
    }
    Wnk[(long)np * 512 + k] = f2bf(v);
}

__global__ __launch_bounds__(512) void k_build_bias(const float* __restrict__ bih,
                                                    const float* __restrict__ bhh,
                                                    const float* __restrict__ bmsg,
                                                    const float* __restrict__ Wih,
                                                    float* __restrict__ bbig,
                                                    float* __restrict__ Bdeg) {
    int np = threadIdx.x;      // 0..511 permuted
    int c = np >> 2, sec = np & 3;
    float b;
    if (sec == 0)      b = bih[c] + bhh[c];
    else if (sec == 1) b = bih[HID + c] + bhh[HID + c];
    else if (sec == 2) b = bih[2 * HID + c];
    else               b = bhh[2 * HID + c];
    bbig[np] = b;
    for (int t = 0; t < 3; t++) {
        float s = 0.f;
        if (sec < 3) {
            const float* wi = Wih + (long)(sec * HID + c) * HID;
            const float* bm = bmsg + t * HID;
            for (int j = 0; j < HID; j++) s += bm[j] * wi[j];
        }
        Bdeg[t * 512 + np] = s;
    }
}

// ---------------------------------------------------------------------------
// Aggregate: one WAVE per node, gather from compact Y [n][128].
// Also copies h (Y row) into X's K-window cols 384..511.
// ---------------------------------------------------------------------------
__global__ __launch_bounds__(256) void k_agg(const unsigned short* __restrict__ Y,
                                             unsigned short* __restrict__ X,
                                             const int* __restrict__ deg,
                                             const int* __restrict__ csr) {
    const int lane = threadIdx.x & 63;
    const long n = (long)blockIdx.x * 4 + (threadIdx.x >> 6);
    const int g = lane >> 4;
    const int c16 = lane & 15;
    const int l31 = lane & 31;

    int d[3], il[3];
#pragma unroll
    for (int t = 0; t < 3; t++) {
        int dt = deg[t * NN + n];
        d[t] = dt > DEG_CAP ? DEG_CAP : dt;
        il[t] = csr[((long)t * NN + n) * DEG_CAP + l31];
    }
#pragma unroll
    for (int t = 0; t < 3; t++) {
        float acc[8] = {0.f, 0.f, 0.f, 0.f, 0.f, 0.f, 0.f, 0.f};
        int rounds = (d[t] + 3) >> 2;
        for (int r = 0; r < rounds; r++) {
            int j = r * 4 + g;
            int idx = __shfl(il[t], j & 31);
            if (j < d[t]) {
                short8 v = *(const short8*)(Y + (long)idx * HID + c16 * 8);
#pragma unroll
                for (int q = 0; q < 8; q++) acc[q] += bf2f((unsigned short)v[q]);
            }
        }
#pragma unroll
        for (int q = 0; q < 8; q++) {
            acc[q] += __shfl_xor(acc[q], 16);
            acc[q] += __shfl_xor(acc[q], 32);
        }
        if (g == 0) {
            short8 o;
#pragma unroll
            for (int q = 0; q < 8; q++) o[q] = (short)f2bf(acc[q]);
            *(short8*)(X + n * XS + t * HID + c16 * 8) = o;
        }
    }
    if (g == 1) {   // h copy: Y row -> X cols 384..511
        short8 v = *(const short8*)(Y + n * HID + c16 * 8);
        *(short8*)(X + n * XS + 384 + c16 * 8) = v;
    }
}

// ---------------------------------------------------------------------------
// Fused GRU step, N-split x4: [A_cat|h] (K=512) x Wnk' (BN=128) + gates.
// BM=128, BN=128, BK=32, 4 waves, wave tile 64x64 (2x2 of 32x32).
// 32 KB LDS (2 x 16KB dbuf) + <=128 VGPR -> 4 blocks/CU: cross-block overlap
// hides the per-iter vmcnt(0) barrier drain (R4/R5 ran 1 block/CU, lockstep).
// global_load_lds staging, linear LDS + pre-swizzled source + swizzled read.
// Epilogue: 4 x 32-row bands through LDS; sec-minor N perm makes gates local.
// h read/written in compact Y (X untouched -> no cross-block aliasing).
// ---------------------------------------------------------------------------
__global__ __launch_bounds__(256, 4) void k_gru_mfma(
        const unsigned short* __restrict__ X,
        const unsigned short* __restrict__ Y,
        unsigned short* __restrict__ Yw,
        const unsigned short* __restrict__ Wnk,
        const float* __restrict__ bbig, const float* __restrict__ Bdeg,
        const int4* __restrict__ degp) {
    __shared__ char lds[32768];     // 2 x (A 8KB + B 8KB)

    const int tid = threadIdx.x;
    const int lane = tid & 63;
    const int wv = tid >> 6;        // 0..3
    const int wr = wv >> 1;         // M half
    const int wc = wv & 1;          // N half
    const int r31 = lane & 31;
    const int kg = lane >> 5;
    const int swr = (r31 >> 1) & 3; // read-side swizzle key
    const int bn = blockIdx.x;      // N quarter
    const long row0 = (long)blockIdx.y * 128;

    f32x16 acc[2][2];
#pragma unroll
    for (int i = 0; i < 2; i++)
#pragma unroll
        for (int j = 0; j < 2; j++) acc[i][j] = (f32x16)(0.0f);

    // staging: pass p in {0,1}; wave wv stages rows p*64 + wv*16 .. +15
    const int lr = lane >> 2, su = lane & 3;
    const int r0_ = wv * 16 + lr;
    const int r1_ = 64 + wv * 16 + lr;
    const char* gA0 = (const char*)X + (row0 + r0_) * 1024 + (su ^ ((r0_ >> 1) & 3)) * 16;
    const char* gA1 = (const char*)X + (row0 + r1_) * 1024 + (su ^ ((r1_ >> 1) & 3)) * 16;
    const char* gB0 = (const char*)Wnk + (long)(bn * 128 + r0_) * 1024 + (su ^ ((r0_ >> 1) & 3)) * 16;
    const char* gB1 = (const char*)Wnk + (long)(bn * 128 + r1_) * 1024 + (su ^ ((r1_ >> 1) & 3)) * 16;
    const int dst0 = (wv * 16) * 64;        // + lane*16 by HW
    const int dst1 = (64 + wv * 16) * 64;

    // prologue: stage buf0 for it=0
    gload16(gA0, lds + dst0);
    gload16(gA1, lds + dst1);
    gload16(gB0, lds + 8192 + dst0);
    gload16(gB1, lds + 8192 + dst1);

    int cur = 0;
    for (int it = 0; it < 16; it++) {
        __syncthreads();            // drains vmcnt(0): buf[cur] ready
        if (it < 15) {
            long ko = (long)(it + 1) * 64;
            char* base = lds + (cur ^ 1) * 16384;
            gload16(gA0 + ko, base + dst0);
            gload16(gA1 + ko, base + dst1);
            gload16(gB0 + ko, base + 8192 + dst0);
            gload16(gB1 + ko, base + 8192 + dst1);
        }
        const char* Al = lds + cur * 16384;
        const char* Bl = Al + 8192;

        short8 af[2][2], bfr[2][2];
#pragma unroll
        for (int rt = 0; rt < 2; rt++)
#pragma unroll
            for (int kb = 0; kb < 2; kb++)
                af[rt][kb] = *(const short8*)(Al + (wr * 64 + rt * 32 + r31) * 64 +
                                              (((2 * kb + kg) ^ swr) * 16));
#pragma unroll
        for (int ct = 0; ct < 2; ct++)
#pragma unroll
            for (int kb = 0; kb < 2; kb++)
                bfr[ct][kb] = *(const short8*)(Bl + (wc * 64 + ct * 32 + r31) * 64 +
                                               (((2 * kb + kg) ^ swr) * 16));
#pragma unroll
        for (int kb = 0; kb < 2; kb++)
#pragma unroll
            for (int rt = 0; rt < 2; rt++)
#pragma unroll
                for (int ct = 0; ct < 2; ct++)
                    acc[rt][ct] = __builtin_amdgcn_mfma_f32_32x32x16_bf16(
                        __builtin_bit_cast(bf16x8, af[rt][kb]),
                        __builtin_bit_cast(bf16x8, bfr[ct][kb]),
                        acc[rt][ct], 0, 0, 0);
        cur ^= 1;
    }

    // ---- epilogue: 4 bands of 32 rows through LDS [32][132] ----
    float* EX = (float*)lds;
#pragma unroll
    for (int band = 0; band < 4; band++) {
        __syncthreads();
        if (wr == (band >> 1)) {
            const int rt = band & 1;
#pragma unroll
            for (int ct = 0; ct < 2; ct++) {
                int col = wc * 64 + ct * 32 + r31;
#pragma unroll
                for (int q = 0; q < 16; q++) {
                    int rw = (q & 3) + 8 * (q >> 2) + 4 * kg;
                    EX[rw * 132 + col] = acc[rt][ct][q];
                }
            }
        }
        __syncthreads();
        {
            int row32 = tid >> 3, chl = tid & 7;
            long grow = row0 + band * 32 + row32;
            int4 dg = degp[grow];
            float dgx = (float)dg.x, dgy = (float)dg.y, dgz = (float)dg.z;
            ushort4 ho = *(const ushort4*)(Y + grow * HID + bn * 32 + chl * 4);
            unsigned short hold[4] = {ho.x, ho.y, ho.z, ho.w};
            ushort4 outp;
            unsigned short* op = (unsigned short*)&outp;
#pragma unroll
            for (int cc = 0; cc < 4; cc++) {
                int np = chl * 16 + cc * 4;     // n'-local: channel chl*4+cc, secs 0..3
                float4 v  = *(const float4*)(EX + row32 * 132 + np);
                float4 bb = *(const float4*)(bbig + bn * 128 + np);
                float4 b0 = *(const float4*)(Bdeg + bn * 128 + np);
                float4 b1 = *(const float4*)(Bdeg + 512 + bn * 128 + np);
                float4 b2 = *(const float4*)(Bdeg + 1024 + bn * 128 + np);
                float Sr = v.x + bb.x + dgx * b0.x + dgy * b1.x + dgz * b2.x;
                float Sz = v.y + bb.y + dgx * b0.y + dgy * b1.y + dgz * b2.y;
                float In = v.z + bb.z + dgx * b0.z + dgy * b1.z + dgz * b2.z;
                float Hn = v.w + bb.w;          // sec3 deg-bias is 0 by construction
                float rr = sigm(Sr);
                float zz = sigm(Sz);
                float tt = In + rr * Hn;
                float e2 = __expf(2.f * tt);
                float nn = 1.f - 2.f / (e2 + 1.f);
                float hv = (1.f - zz) * nn + zz * bf2f(hold[cc]);
                op[cc] = f2bf(hv);
            }
            *(ushort4*)(Yw + grow * HID + bn * 32 + chl * 4) = outp;
        }
    }
}

// ---------------------------------------------------------------------------
// Readout: out[g] += sigmoid(h@Wg.T+bg) * (h@Wp.T+bp). h from Y bf16.
// ---------------------------------------------------------------------------
__global__ __launch_bounds__(256) void k_readout(const unsigned short* __restrict__ Y,
                                                 const int* __restrict__ n2g,
                                                 const float* __restrict__ Wp,
                                                 const float* __restrict__ bp,
                                                 const float* __restrict__ Wg,
                                                 const float* __restrict__ bg,
                                                 float* __restrict__ out) {
    __shared__ float hs[32][132];
    __shared__ float Ws[64][129];
    int tid = threadIdx.x;
    long row0 = (long)blockIdx.x * 32;
    int rg = tid >> 5, cg = tid & 31;
    float acc[4][4];
#pragma unroll
    for (int r = 0; r < 4; r++)
#pragma unroll
        for (int c = 0; c < 4; c++) acc[r][c] = 0.f;

#pragma unroll
    for (int p = 0; p < 2; p++) {
        int e = p * 256 + tid;
        int r = e >> 4, c8 = e & 15;
        short8 v = *(const short8*)(Y + (row0 + r) * HID + c8 * 8);
#pragma unroll
        for (int j = 0; j < 8; j++) hs[r][c8 * 8 + j] = bf2f((unsigned short)v[j]);
    }
    for (int kc = 0; kc < 128; kc += 64) {
        __syncthreads();
#pragma unroll
        for (int p = 0; p < 8; p++) {
            int idx = p * 256 + tid;
            int j = idx >> 4, q = idx & 15;
            const float* Wsrc = (j < 64) ? Wp : Wg;
            float4 w = *(const float4*)&Wsrc[(j & 63) * HID + kc + q * 4];
            Ws[q * 4 + 0][j] = w.x;
            Ws[q * 4 + 1][j] = w.y;
            Ws[q * 4 + 2][j] = w.z;
            Ws[q * 4 + 3][j] = w.w;
        }
        __syncthreads();
#pragma unroll 8
        for (int k = 0; k < 64; k++) {
            float a[4], w[4];
#pragma unroll
            for (int r = 0; r < 4; r++) a[r] = hs[rg * 4 + r][kc + k];
#pragma unroll
            for (int c = 0; c < 4; c++) w[c] = Ws[k][cg + 32 * c];
#pragma unroll
            for (int r = 0; r < 4; r++)
#pragma unroll
                for (int c = 0; c < 4; c++) acc[r][c] += a[r] * w[c];
        }
    }
#pragma unroll
    for (int r = 0; r < 4; r++) {
        long row = row0 + rg * 4 + r;
        if (row < NN) {
            int g = n2g[row];
            float pv0 = acc[r][0] + bp[cg];
            float pv1 = acc[r][1] + bp[cg + 32];
            float gv0 = acc[r][2] + bg[cg];
            float gv1 = acc[r][3] + bg[cg + 32];
            atomicAdd(&out[g * EMB + cg],      pv0 * sigm(gv0));
            atomicAdd(&out[g * EMB + cg + 32], pv1 * sigm(gv1));
        }
    }
}

// ---------------------------------------------------------------------------
extern "C" void kernel_launch(void* const* d_in, const int* in_sizes, int n_in,
                              void* d_out, int out_size, void* d_ws, size_t ws_size,
                              hipStream_t stream) {
    const float* node_features = (const float*)d_in[0];
    const int*   edge_index    = (const int*)d_in[1];
    const int*   n2g           = (const int*)d_in[2];
    const float* W_msg         = (const float*)d_in[3];
    const float* b_msg         = (const float*)d_in[4];
    const float* W_ih          = (const float*)d_in[5];
    const float* W_hh          = (const float*)d_in[6];
    const float* b_ih          = (const float*)d_in[7];
    const float* b_hh          = (const float*)d_in[8];
    const float* W_proj        = (const float*)d_in[9];
    const float* b_proj        = (const float*)d_in[10];
    const float* W_gate        = (const float*)d_in[11];
    const float* b_gate        = (const float*)d_in[12];

    char* ws = (char*)d_ws;
    unsigned short* X    = (unsigned short*)(ws);                 // 102,498,304 B
    unsigned short* Y    = (unsigned short*)(ws + 102498304);     //  25,624,576 B
    unsigned short* Wnk  = (unsigned short*)(ws + 128122880);     //     524,288 B
    float*          bbig = (float*)         (ws + 128647168);     //       2,048 B
    float*          Bdeg = (float*)         (ws + 128649216);     //       6,144 B
    int4*           degp = (int4*)          (ws + 128655360);     //   1,601,536 B
    int*            deg  = (int*)           (ws + 130256896);     //   1,200,000 B
    int*            csr  = (int*)           (ws + 131456896);     //  38,400,000 B -> 169,856,896

    float* out = (float*)d_out;

    hipMemsetAsync(out, 0, (size_t)NG * EMB * sizeof(float), stream);
    hipMemsetAsync(deg, 0, (size_t)3 * NN * sizeof(int), stream);

    k_init<<<dim3((NNP * HID) / 256), dim3(256), 0, stream>>>(node_features, Y);
    k_build_csr<<<dim3((3 * NE + 255) / 256), dim3(256), 0, stream>>>(edge_index, deg, csr);
    k_pack_deg<<<dim3(NNP / 256), dim3(256), 0, stream>>>(deg, degp);
    k_build_w<<<dim3(512), dim3(512), 0, stream>>>(W_msg, W_ih, W_hh, Wnk);
    k_build_bias<<<dim3(1), dim3(512), 0, stream>>>(b_ih, b_hh, b_msg, W_ih, bbig, Bdeg);

    for (int step = 0; step < 4; step++) {
        k_agg<<<dim3(NN / 4), dim3(256), 0, stream>>>(Y, X, deg, csr);
        k_gru_mfma<<<dim3(4, NNP / 128), dim3(256), 0, stream>>>(X, Y, Y, Wnk, bbig, Bdeg, degp);
    }
    k_readout<<<dim3(NN / 32), dim3(256), 0, stream>>>(Y, n2g, W_proj, b_proj,
                                                       W_gate, b_gate, out);
}

// Round 7
// 928.276 us; speedup vs baseline: 1.0810x; 1.0810x over previous
//
#include <hip/hip_runtime.h>
#include <hip/hip_bf16.h>
#include <math.h>

#define NN 100000
#define NNP 100096          // padded to 782*128
#define NE 300000
#define HID 128
#define EMB 64
#define NG 4096
#define DEG_CAP 32
#define XS 512              // X row stride in elements

typedef __bf16 bf16x8 __attribute__((ext_vector_type(8)));
typedef float  f32x16 __attribute__((ext_vector_type(16)));
typedef short  short8 __attribute__((ext_vector_type(8)));

typedef const __attribute__((address_space(1))) unsigned int* gas_u32;
typedef __attribute__((address_space(3))) unsigned int* las_u32;

__device__ __forceinline__ void gload16(const void* g, void* l) {
    // async global->LDS DMA, 16B/lane; LDS dest = wave-uniform base + lane*16
    __builtin_amdgcn_global_load_lds((gas_u32)g, (las_u32)l, 16, 0, 0);
}

__device__ __forceinline__ float bf2f(unsigned short u) {
    unsigned int x = ((unsigned int)u) << 16;
    return __builtin_bit_cast(float, x);
}
__device__ __forceinline__ unsigned short f2bf(float f) {
    unsigned int x = __builtin_bit_cast(unsigned int, f);
    unsigned int r = x + 0x7fff + ((x >> 16) & 1);
    return (unsigned short)(r >> 16);
}
__device__ __forceinline__ float sigm(float x) { return 1.f / (1.f + __expf(-x)); }

// ---------------------------------------------------------------------------
// h init: node_features f32 -> Y bf16 [NNP][128] AND X h-window cols 384..511.
// ---------------------------------------------------------------------------
__global__ __launch_bounds__(256) void k_init(const float* __restrict__ nf,
                                              unsigned short* __restrict__ Y,
                                              unsigned short* __restrict__ X) {
    int id = blockIdx.x * 256 + threadIdx.x;   // NNP*HID
    int n = id >> 7, c = id & 127;
    unsigned short hv = (n < NN) ? f2bf(nf[(long)n * HID + c]) : (unsigned short)0;
    Y[(long)n * HID + c] = hv;
    X[(long)n * XS + 384 + c] = hv;
}

// ---------------------------------------------------------------------------
// CSR build (deg true counts; csr capped at DEG_CAP)
// ---------------------------------------------------------------------------
__global__ __launch_bounds__(256) void k_build_csr(const int* __restrict__ ei,
                                                   int* __restrict__ deg,
                                                   int* __restrict__ csr) {
    int id = blockIdx.x * 256 + threadIdx.x;
    if (id >= 3 * NE) return;
    int t = id / NE;
    int i = id - t * NE;
    int src = ei[(t * 2 + 0) * NE + i];
    int dst = ei[(t * 2 + 1) * NE + i];
    int p = atomicAdd(&deg[t * NN + dst], 1);
    if (p < DEG_CAP) csr[((long)t * NN + dst) * DEG_CAP + p] = src;
}

__global__ __launch_bounds__(256) void k_pack_deg(const int* __restrict__ deg,
                                                  int4* __restrict__ degp) {
    int n = blockIdx.x * 256 + threadIdx.x;
    if (n >= NNP) return;
    int4 v; v.x = 0; v.y = 0; v.z = 0; v.w = 0;
    if (n < NN) { v.x = deg[n]; v.y = deg[NN + n]; v.z = deg[2 * NN + n]; }
    degp[n] = v;
}

// ---------------------------------------------------------------------------
// Bf: FRAGMENT-ORDERED weights. n' = c*4 + sec (sec-minor). For MFMA
// 32x32x16 B-operand, lane = kg*32 + nl supplies B[n' = nb*32+nl]
// [k = k16*16 + kg*8 + e]. Fragment (nb,k16) = contiguous 1KB:
// Bf[(((nb*32 + k16)*64 + kg*32 + nl))*8 + e].
// K layout: k<384 -> A_cat (Wm @ Wih_sec^T), k>=384 -> h (Whh_sec).
// ---------------------------------------------------------------------------
__global__ __launch_bounds__(512) void k_build_w(const float* __restrict__ Wmsg,
                                                 const float* __restrict__ Wih,
                                                 const float* __restrict__ Whh,
                                                 unsigned short* __restrict__ Bf) {
    int np = blockIdx.x;       // 0..511 permuted col
    int k = threadIdx.x;       // 0..511
    int c = np >> 2, sec = np & 3;
    float v = 0.f;
    if (k < 384) {
        if (sec < 3) {
            int t = k >> 7, kk = k & 127;
            const float* wm = Wmsg + ((long)t * HID + kk) * HID;
            const float* wi = Wih + (long)(sec * HID + c) * HID;
            float s = 0.f;
            for (int j = 0; j < HID; j++) s += wm[j] * wi[j];
            v = s;
        }
    } else {
        int kk = k - 384;
        if (sec == 0)      v = Whh[(long)c * HID + kk];
        else if (sec == 1) v = Whh[(long)(HID + c) * HID + kk];
        else if (sec == 3) v = Whh[(long)(2 * HID + c) * HID + kk];
    }
    int nb = np >> 5, nl = np & 31;
    int k16 = k >> 4, kgg = (k >> 3) & 1, e = k & 7;
    Bf[((((nb * 32 + k16) * 2 + kgg) * 32 + nl) << 3) + e] = f2bf(v);
}

__global__ __launch_bounds__(512) void k_build_bias(const float* __restrict__ bih,
                                                    const float* __restrict__ bhh,
                                                    const float* __restrict__ bmsg,
                                                    const float* __restrict__ Wih,
                                                    float* __restrict__ bbig,
                                                    float* __restrict__ Bdeg) {
    int np = threadIdx.x;      // 0..511 permuted
    int c = np >> 2, sec = np & 3;
    float b;
    if (sec == 0)      b = bih[c] + bhh[c];
    else if (sec == 1) b = bih[HID + c] + bhh[HID + c];
    else if (sec == 2) b = bih[2 * HID + c];
    else               b = bhh[2 * HID + c];
    bbig[np] = b;
    for (int t = 0; t < 3; t++) {
        float s = 0.f;
        if (sec < 3) {
            const float* wi = Wih + (long)(sec * HID + c) * HID;
            const float* bm = bmsg + t * HID;
            for (int j = 0; j < HID; j++) s += bm[j] * wi[j];
        }
        Bdeg[t * 512 + np] = s;
    }
}

// ---------------------------------------------------------------------------
// Aggregate: one WAVE per node, gather from compact Y [n][128], write A_cat
// into X cols 0..383. (h-window of X is maintained by k_init / gru epilogue.)
// ---------------------------------------------------------------------------
__global__ __launch_bounds__(256) void k_agg(const unsigned short* __restrict__ Y,
                                             unsigned short* __restrict__ X,
                                             const int* __restrict__ deg,
                                             const int* __restrict__ csr) {
    const int lane = threadIdx.x & 63;
    const long n = (long)blockIdx.x * 4 + (threadIdx.x >> 6);
    const int g = lane >> 4;
    const int c16 = lane & 15;
    const int l31 = lane & 31;

    int d[3], il[3];
#pragma unroll
    for (int t = 0; t < 3; t++) {
        int dt = deg[t * NN + n];
        d[t] = dt > DEG_CAP ? DEG_CAP : dt;
        il[t] = csr[((long)t * NN + n) * DEG_CAP + l31];
    }
#pragma unroll
    for (int t = 0; t < 3; t++) {
        float acc[8] = {0.f, 0.f, 0.f, 0.f, 0.f, 0.f, 0.f, 0.f};
        int rounds = (d[t] + 3) >> 2;
        for (int r = 0; r < rounds; r++) {
            int j = r * 4 + g;
            int idx = __shfl(il[t], j & 31);
            if (j < d[t]) {
                short8 v = *(const short8*)(Y + (long)idx * HID + c16 * 8);
#pragma unroll
                for (int q = 0; q < 8; q++) acc[q] += bf2f((unsigned short)v[q]);
            }
        }
#pragma unroll
        for (int q = 0; q < 8; q++) {
            acc[q] += __shfl_xor(acc[q], 16);
            acc[q] += __shfl_xor(acc[q], 32);
        }
        if (g == 0) {
            short8 o;
#pragma unroll
            for (int q = 0; q < 8; q++) o[q] = (short)f2bf(acc[q]);
            *(short8*)(X + n * XS + t * HID + c16 * 8) = o;
        }
    }
}

// ---------------------------------------------------------------------------
// Fused GRU step: [A_cat|h] (K=512) x Bf (N=512) + gates.
// BM=128, BN=512, 8 waves (2M x 4N), wave tile 64x128 (2x4 of 32x32).
// A-tile lives in LDS, staged ONCE per 256-K-half via global_load_lds with
// per-lane fragment-transposing source addresses -> conflict-free ds_read_b128
// with immediate offsets, NO per-iteration barriers (3 barriers total in loop).
// B read directly from L2 (512KB resident) via fragment-ordered coalesced
// 1KB wave-loads. MFMA-bound target: ~21us floor.
// Epilogue: 4 bands of 32 rows through 64KB LDS; writes h to Y and X h-window.
// ---------------------------------------------------------------------------
__global__ __launch_bounds__(512, 2) void k_gru_mfma(
        const unsigned short* __restrict__ X,
        unsigned short* __restrict__ Xh,
        const unsigned short* __restrict__ Y,
        unsigned short* __restrict__ Yw,
        const unsigned short* __restrict__ Bf,
        const float* __restrict__ bbig, const float* __restrict__ Bdeg,
        const int4* __restrict__ degp) {
    __shared__ char lds[65536];     // A-half tile [k16 16][kg 2][row 128][16B]; reused as EX

    const int tid = threadIdx.x;
    const int lane = tid & 63;
    const int wv = tid >> 6;        // 0..7
    const int wr = wv >> 2;         // M half
    const int wc = wv & 3;          // N quarter
    const int r31 = lane & 31;
    const int kg = lane >> 5;
    const long row0 = (long)blockIdx.x * 128;

    f32x16 acc[2][4];
#pragma unroll
    for (int i = 0; i < 2; i++)
#pragma unroll
        for (int j = 0; j < 4; j++) acc[i][j] = (f32x16)(0.0f);

    // A staging: inst (wv,jj) -> LDS Fidx = (wv*8+jj)*64 + lane, decoding
    // row = 64*(jj&1)+lane(mod), kg=(jj>>1)&1, kl = wv*2+(jj>>2).
    const char* pA = (const char*)X + (row0 + lane) * 1024;
#define STAGE_A(H)                                                              \
    {                                                                           \
        _Pragma("unroll")                                                       \
        for (int jj = 0; jj < 8; jj++) {                                        \
            gload16(pA + ((jj & 1) * 65536 + (H) * 512 +                        \
                          (wv * 2 + (jj >> 2)) * 32 + ((jj >> 1) & 1) * 16),    \
                    lds + (wv * 8 + jj) * 1024);                                \
        }                                                                       \
    }

    // B fragment base pointers (ushort units), coalesced 16B/lane
    const unsigned short* pB0 = Bf + (wc * 4 + 0) * 16384 + lane * 8;
    const unsigned short* pB1 = Bf + (wc * 4 + 1) * 16384 + lane * 8;
    const unsigned short* pB2 = Bf + (wc * 4 + 2) * 16384 + lane * 8;
    const unsigned short* pB3 = Bf + (wc * 4 + 3) * 16384 + lane * 8;

    // LDS read base for A fragments (per-lane, loop-invariant)
    const int vAoff = kg * 2048 + wr * 1024 + r31 * 16;
    const char* ldsA = lds;

    STAGE_A(0);
    __syncthreads();

#pragma unroll
    for (int it = 0; it < 16; it++) {
        if (it == 8) {
            __syncthreads();
            STAGE_A(1);
            __syncthreads();
        }
#pragma unroll
        for (int kb = 0; kb < 2; kb++) {
            const int kl = (it & 7) * 2 + kb;    // local k16 (0..15)
            const int k16 = it * 2 + kb;         // global k16 (0..31)
            short8 af0 = *(const short8*)(ldsA + kl * 4096 + vAoff);        // rt=0
            short8 af1 = *(const short8*)(ldsA + kl * 4096 + 512 + vAoff);  // rt=1
            short8 b0 = *(const short8*)(pB0 + k16 * 512);
            short8 b1 = *(const short8*)(pB1 + k16 * 512);
            short8 b2 = *(const short8*)(pB2 + k16 * 512);
            short8 b3 = *(const short8*)(pB3 + k16 * 512);
            acc[0][0] = __builtin_amdgcn_mfma_f32_32x32x16_bf16(
                __builtin_bit_cast(bf16x8, af0), __builtin_bit_cast(bf16x8, b0), acc[0][0], 0, 0, 0);
            acc[0][1] = __builtin_amdgcn_mfma_f32_32x32x16_bf16(
                __builtin_bit_cast(bf16x8, af0), __builtin_bit_cast(bf16x8, b1), acc[0][1], 0, 0, 0);
            acc[0][2] = __builtin_amdgcn_mfma_f32_32x32x16_bf16(
                __builtin_bit_cast(bf16x8, af0), __builtin_bit_cast(bf16x8, b2), acc[0][2], 0, 0, 0);
            acc[0][3] = __builtin_amdgcn_mfma_f32_32x32x16_bf16(
                __builtin_bit_cast(bf16x8, af0), __builtin_bit_cast(bf16x8, b3), acc[0][3], 0, 0, 0);
            acc[1][0] = __builtin_amdgcn_mfma_f32_32x32x16_bf16(
                __builtin_bit_cast(bf16x8, af1), __builtin_bit_cast(bf16x8, b0), acc[1][0], 0, 0, 0);
            acc[1][1] = __builtin_amdgcn_mfma_f32_32x32x16_bf16(
                __builtin_bit_cast(bf16x8, af1), __builtin_bit_cast(bf16x8, b1), acc[1][1], 0, 0, 0);
            acc[1][2] = __builtin_amdgcn_mfma_f32_32x32x16_bf16(
                __builtin_bit_cast(bf16x8, af1), __builtin_bit_cast(bf16x8, b2), acc[1][2], 0, 0, 0);
            acc[1][3] = __builtin_amdgcn_mfma_f32_32x32x16_bf16(
                __builtin_bit_cast(bf16x8, af1), __builtin_bit_cast(bf16x8, b3), acc[1][3], 0, 0, 0);
        }
    }

    // ---- epilogue: 4 bands of 32 rows; EX = [32][512] f32 = 64KB ----
    float* EX = (float*)lds;
    const int ch = tid & 127;               // channel 0..127
    const int rbase = tid >> 7;             // 0..3
    const float4 bb = *(const float4*)(bbig + ch * 4);
    const float4 e0 = *(const float4*)(Bdeg + ch * 4);
    const float4 e1 = *(const float4*)(Bdeg + 512 + ch * 4);
    const float4 e2 = *(const float4*)(Bdeg + 1024 + ch * 4);

#pragma unroll
    for (int b = 0; b < 4; b++) {
        __syncthreads();
        if (wr == (b >> 1)) {
            const int rt = b & 1;
#pragma unroll
            for (int ct = 0; ct < 4; ct++) {
                int col = wc * 128 + ct * 32 + r31;
#pragma unroll
                for (int q = 0; q < 16; q++) {
                    int rw = (q & 3) + 8 * (q >> 2) + 4 * kg;
                    EX[rw * 512 + col] = acc[rt][ct][q];
                }
            }
        }
        __syncthreads();
#pragma unroll
        for (int i = 0; i < 8; i++) {
            int rw = rbase + 4 * i;
            long grow = row0 + b * 32 + rw;
            int4 dg = degp[grow];
            float dgx = (float)dg.x, dgy = (float)dg.y, dgz = (float)dg.z;
            float4 v = *(const float4*)(EX + rw * 512 + ch * 4);
            float Sr = v.x + bb.x + dgx * e0.x + dgy * e1.x + dgz * e2.x;
            float Sz = v.y + bb.y + dgx * e0.y + dgy * e1.y + dgz * e2.y;
            float In = v.z + bb.z + dgx * e0.z + dgy * e1.z + dgz * e2.z;
            float Hn = v.w + bb.w;      // sec3 deg-bias is 0 by construction
            float rr = sigm(Sr);
            float zz = sigm(Sz);
            float tt = In + rr * Hn;
            float ee = __expf(2.f * tt);
            float nn = 1.f - 2.f / (ee + 1.f);
            float hv = (1.f - zz) * nn + zz * bf2f(Y[grow * HID + ch]);
            unsigned short hb = f2bf(hv);
            Yw[grow * HID + ch] = hb;
            Xh[grow * XS + 384 + ch] = hb;
        }
    }
}

// ---------------------------------------------------------------------------
// Readout: out[g] += sigmoid(h@Wg.T+bg) * (h@Wp.T+bp). h from Y bf16.
// ---------------------------------------------------------------------------
__global__ __launch_bounds__(256) void k_readout(const unsigned short* __restrict__ Y,
                                                 const int* __restrict__ n2g,
                                                 const float* __restrict__ Wp,
                                                 const float* __restrict__ bp,
                                                 const float* __restrict__ Wg,
                                                 const float* __restrict__ bg,
                                                 float* __restrict__ out) {
    __shared__ float hs[32][132];
    __shared__ float Ws[64][129];
    int tid = threadIdx.x;
    long row0 = (long)blockIdx.x * 32;
    int rg = tid >> 5, cg = tid & 31;
    float acc[4][4];
#pragma unroll
    for (int r = 0; r < 4; r++)
#pragma unroll
        for (int c = 0; c < 4; c++) acc[r][c] = 0.f;

#pragma unroll
    for (int p = 0; p < 2; p++) {
        int e = p * 256 + tid;
        int r = e >> 4, c8 = e & 15;
        short8 v = *(const short8*)(Y + (row0 + r) * HID + c8 * 8);
#pragma unroll
        for (int j = 0; j < 8; j++) hs[r][c8 * 8 + j] = bf2f((unsigned short)v[j]);
    }
    for (int kc = 0; kc < 128; kc += 64) {
        __syncthreads();
#pragma unroll
        for (int p = 0; p < 8; p++) {
            int idx = p * 256 + tid;
            int j = idx >> 4, q = idx & 15;
            const float* Wsrc = (j < 64) ? Wp : Wg;
            float4 w = *(const float4*)&Wsrc[(j & 63) * HID + kc + q * 4];
            Ws[q * 4 + 0][j] = w.x;
            Ws[q * 4 + 1][j] = w.y;
            Ws[q * 4 + 2][j] = w.z;
            Ws[q * 4 + 3][j] = w.w;
        }
        __syncthreads();
#pragma unroll 8
        for (int k = 0; k < 64; k++) {
            float a[4], w[4];
#pragma unroll
            for (int r = 0; r < 4; r++) a[r] = hs[rg * 4 + r][kc + k];
#pragma unroll
            for (int c = 0; c < 4; c++) w[c] = Ws[k][cg + 32 * c];
#pragma unroll
            for (int r = 0; r < 4; r++)
#pragma unroll
                for (int c = 0; c < 4; c++) acc[r][c] += a[r] * w[c];
        }
    }
#pragma unroll
    for (int r = 0; r < 4; r++) {
        long row = row0 + rg * 4 + r;
        if (row < NN) {
            int g = n2g[row];
            float pv0 = acc[r][0] + bp[cg];
            float pv1 = acc[r][1] + bp[cg + 32];
            float gv0 = acc[r][2] + bg[cg];
            float gv1 = acc[r][3] + bg[cg + 32];
            atomicAdd(&out[g * EMB + cg],      pv0 * sigm(gv0));
            atomicAdd(&out[g * EMB + cg + 32], pv1 * sigm(gv1));
        }
    }
}

// ---------------------------------------------------------------------------
extern "C" void kernel_launch(void* const* d_in, const int* in_sizes, int n_in,
                              void* d_out, int out_size, void* d_ws, size_t ws_size,
                              hipStream_t stream) {
    const float* node_features = (const float*)d_in[0];
    const int*   edge_index    = (const int*)d_in[1];
    const int*   n2g           = (const int*)d_in[2];
    const float* W_msg         = (const float*)d_in[3];
    const float* b_msg         = (const float*)d_in[4];
    const float* W_ih          = (const float*)d_in[5];
    const float* W_hh          = (const float*)d_in[6];
    const float* b_ih          = (const float*)d_in[7];
    const float* b_hh          = (const float*)d_in[8];
    const float* W_proj        = (const float*)d_in[9];
    const float* b_proj        = (const float*)d_in[10];
    const float* W_gate        = (const float*)d_in[11];
    const float* b_gate        = (const float*)d_in[12];

    char* ws = (char*)d_ws;
    unsigned short* X    = (unsigned short*)(ws);                 // 102,498,304 B
    unsigned short* Y    = (unsigned short*)(ws + 102498304);     //  25,624,576 B
    unsigned short* Bf   = (unsigned short*)(ws + 128122880);     //     524,288 B
    float*          bbig = (float*)         (ws + 128647168);     //       2,048 B
    float*          Bdeg = (float*)         (ws + 128649216);     //       6,144 B
    int4*           degp = (int4*)          (ws + 128655360);     //   1,601,536 B
    int*            deg  = (int*)           (ws + 130256896);     //   1,200,000 B
    int*            csr  = (int*)           (ws + 131456896);     //  38,400,000 B -> 169,856,896

    float* out = (float*)d_out;

    hipMemsetAsync(out, 0, (size_t)NG * EMB * sizeof(float), stream);
    hipMemsetAsync(deg, 0, (size_t)3 * NN * sizeof(int), stream);

    k_init<<<dim3((NNP * HID) / 256), dim3(256), 0, stream>>>(node_features, Y, X);
    k_build_csr<<<dim3((3 * NE + 255) / 256), dim3(256), 0, stream>>>(edge_index, deg, csr);
    k_pack_deg<<<dim3(NNP / 256), dim3(256), 0, stream>>>(deg, degp);
    k_build_w<<<dim3(512), dim3(512), 0, stream>>>(W_msg, W_ih, W_hh, Bf);
    k_build_bias<<<dim3(1), dim3(512), 0, stream>>>(b_ih, b_hh, b_msg, W_ih, bbig, Bdeg);

    for (int step = 0; step < 4; step++) {
        k_agg<<<dim3(NN / 4), dim3(256), 0, stream>>>(Y, X, deg, csr);
        k_gru_mfma<<<dim3(NNP / 128), dim3(512), 0, stream>>>(X, X, Y, Y, Bf,
                                                              bbig, Bdeg, degp);
    }
    k_readout<<<dim3(NN / 32), dim3(256), 0, stream>>>(Y, n2g, W_proj, b_proj,
                                                       W_gate, b_gate, out);
}

// Round 8
// 824.095 us; speedup vs baseline: 1.2176x; 1.1264x over previous
//
#include <hip/hip_runtime.h>
#include <hip/hip_bf16.h>
#include <math.h>

#define NN 100000
#define NNP 100096          // padded to 782*128 (and 1564*64)
#define NE 300000
#define HID 128
#define EMB 64
#define NG 4096
#define DEG_CAP 32
#define XS 512              // X row stride in elements

typedef __bf16 bf16x8 __attribute__((ext_vector_type(8)));
typedef float  f32x16 __attribute__((ext_vector_type(16)));
typedef short  short8 __attribute__((ext_vector_type(8)));

typedef const __attribute__((address_space(1))) unsigned int* gas_u32;
typedef __attribute__((address_space(3))) unsigned int* las_u32;

__device__ __forceinline__ void gload16(const void* g, void* l) {
    // async global->LDS DMA, 16B/lane; LDS dest = wave-uniform base + lane*16
    __builtin_amdgcn_global_load_lds((gas_u32)g, (las_u32)l, 16, 0, 0);
}

__device__ __forceinline__ float bf2f(unsigned short u) {
    unsigned int x = ((unsigned int)u) << 16;
    return __builtin_bit_cast(float, x);
}
__device__ __forceinline__ unsigned short f2bf(float f) {
    unsigned int x = __builtin_bit_cast(unsigned int, f);
    unsigned int r = x + 0x7fff + ((x >> 16) & 1);
    return (unsigned short)(r >> 16);
}
__device__ __forceinline__ float sigm(float x) { return 1.f / (1.f + __expf(-x)); }

// ---------------------------------------------------------------------------
// h init: node_features f32 -> Y bf16 [NNP][128] AND X h-window cols 384..511.
// ---------------------------------------------------------------------------
__global__ __launch_bounds__(256) void k_init(const float* __restrict__ nf,
                                              unsigned short* __restrict__ Y,
                                              unsigned short* __restrict__ X) {
    int id = blockIdx.x * 256 + threadIdx.x;   // NNP*HID
    int n = id >> 7, c = id & 127;
    unsigned short hv = (n < NN) ? f2bf(nf[(long)n * HID + c]) : (unsigned short)0;
    Y[(long)n * HID + c] = hv;
    X[(long)n * XS + 384 + c] = hv;
}

// ---------------------------------------------------------------------------
// CSR build (deg true counts; csr capped at DEG_CAP)
// ---------------------------------------------------------------------------
__global__ __launch_bounds__(256) void k_build_csr(const int* __restrict__ ei,
                                                   int* __restrict__ deg,
                                                   int* __restrict__ csr) {
    int id = blockIdx.x * 256 + threadIdx.x;
    if (id >= 3 * NE) return;
    int t = id / NE;
    int i = id - t * NE;
    int src = ei[(t * 2 + 0) * NE + i];
    int dst = ei[(t * 2 + 1) * NE + i];
    int p = atomicAdd(&deg[t * NN + dst], 1);
    if (p < DEG_CAP) csr[((long)t * NN + dst) * DEG_CAP + p] = src;
}

__global__ __launch_bounds__(256) void k_pack_deg(const int* __restrict__ deg,
                                                  int4* __restrict__ degp) {
    int n = blockIdx.x * 256 + threadIdx.x;
    if (n >= NNP) return;
    int4 v; v.x = 0; v.y = 0; v.z = 0; v.w = 0;
    if (n < NN) { v.x = deg[n]; v.y = deg[NN + n]; v.z = deg[2 * NN + n]; }
    degp[n] = v;
}

// ---------------------------------------------------------------------------
// Bf: FRAGMENT-ORDERED weights. n' = c*4 + sec (sec-minor). For MFMA
// 32x32x16 B-operand, lane = kg*32 + nl supplies B[n' = nb*32+nl]
// [k = k16*16 + kg*8 + e]. Fragment (nb,k16) = contiguous 1KB:
// Bf[(((nb*32 + k16)*64 + kg*32 + nl))*8 + e].
// K layout: k<384 -> A_cat (Wm @ Wih_sec^T), k>=384 -> h (Whh_sec).
// ---------------------------------------------------------------------------
__global__ __launch_bounds__(512) void k_build_w(const float* __restrict__ Wmsg,
                                                 const float* __restrict__ Wih,
                                                 const float* __restrict__ Whh,
                                                 unsigned short* __restrict__ Bf) {
    int np = blockIdx.x;       // 0..511 permuted col
    int k = threadIdx.x;       // 0..511
    int c = np >> 2, sec = np & 3;
    float v = 0.f;
    if (k < 384) {
        if (sec < 3) {
            int t = k >> 7, kk = k & 127;
            const float* wm = Wmsg + ((long)t * HID + kk) * HID;
            const float* wi = Wih + (long)(sec * HID + c) * HID;
            float s = 0.f;
            for (int j = 0; j < HID; j++) s += wm[j] * wi[j];
            v = s;
        }
    } else {
        int kk = k - 384;
        if (sec == 0)      v = Whh[(long)c * HID + kk];
        else if (sec == 1) v = Whh[(long)(HID + c) * HID + kk];
        else if (sec == 3) v = Whh[(long)(2 * HID + c) * HID + kk];
    }
    int nb = np >> 5, nl = np & 31;
    int k16 = k >> 4, kgg = (k >> 3) & 1, e = k & 7;
    Bf[((((nb * 32 + k16) * 2 + kgg) * 32 + nl) << 3) + e] = f2bf(v);
}

__global__ __launch_bounds__(512) void k_build_bias(const float* __restrict__ bih,
                                                    const float* __restrict__ bhh,
                                                    const float* __restrict__ bmsg,
                                                    const float* __restrict__ Wih,
                                                    float* __restrict__ bbig,
                                                    float* __restrict__ Bdeg) {
    int np = threadIdx.x;      // 0..511 permuted
    int c = np >> 2, sec = np & 3;
    float b;
    if (sec == 0)      b = bih[c] + bhh[c];
    else if (sec == 1) b = bih[HID + c] + bhh[HID + c];
    else if (sec == 2) b = bih[2 * HID + c];
    else               b = bhh[2 * HID + c];
    bbig[np] = b;
    for (int t = 0; t < 3; t++) {
        float s = 0.f;
        if (sec < 3) {
            const float* wi = Wih + (long)(sec * HID + c) * HID;
            const float* bm = bmsg + t * HID;
            for (int j = 0; j < HID; j++) s += bm[j] * wi[j];
        }
        Bdeg[t * 512 + np] = s;
    }
}

// ---------------------------------------------------------------------------
// Aggregate: one WAVE per node, gather from compact Y [n][128], write A_cat
// into X cols 0..383. (h-window of X is maintained by k_init / gru epilogue.)
// ---------------------------------------------------------------------------
__global__ __launch_bounds__(256) void k_agg(const unsigned short* __restrict__ Y,
                                             unsigned short* __restrict__ X,
                                             const int* __restrict__ deg,
                                             const int* __restrict__ csr) {
    const int lane = threadIdx.x & 63;
    const long n = (long)blockIdx.x * 4 + (threadIdx.x >> 6);
    const int g = lane >> 4;
    const int c16 = lane & 15;
    const int l31 = lane & 31;

    int d[3], il[3];
#pragma unroll
    for (int t = 0; t < 3; t++) {
        int dt = deg[t * NN + n];
        d[t] = dt > DEG_CAP ? DEG_CAP : dt;
        il[t] = csr[((long)t * NN + n) * DEG_CAP + l31];
    }
#pragma unroll
    for (int t = 0; t < 3; t++) {
        float acc[8] = {0.f, 0.f, 0.f, 0.f, 0.f, 0.f, 0.f, 0.f};
        int rounds = (d[t] + 3) >> 2;
        for (int r = 0; r < rounds; r++) {
            int j = r * 4 + g;
            int idx = __shfl(il[t], j & 31);
            if (j < d[t]) {
                short8 v = *(const short8*)(Y + (long)idx * HID + c16 * 8);
#pragma unroll
                for (int q = 0; q < 8; q++) acc[q] += bf2f((unsigned short)v[q]);
            }
        }
#pragma unroll
        for (int q = 0; q < 8; q++) {
            acc[q] += __shfl_xor(acc[q], 16);
            acc[q] += __shfl_xor(acc[q], 32);
        }
        if (g == 0) {
            short8 o;
#pragma unroll
            for (int q = 0; q < 8; q++) o[q] = (short)f2bf(acc[q]);
            *(short8*)(X + n * XS + t * HID + c16 * 8) = o;
        }
    }
}

// ---------------------------------------------------------------------------
// Fused GRU step: [A_cat|h] (K=512) x Bf (N=512) + gates.
// BM=64, BN=512, 8 waves (1 N-slot each), wave tile 64x64 (2x2 of 32x32):
// acc = 64 AGPR + ~50 VGPR <= 128 unified regs -> 4 waves/SIMD (R3-R7 ran
// 232 regs -> 2 waves/SIMD -> latency-starved at 13% MfmaUtil).
// A staged once per 256-K half (32KB LDS, fragment-transposed DMA ->
// conflict-free ds_read_b128); B from L2, fragment-ordered coalesced loads;
// each wave reads distinct B cols (B once/block). Grid 1564.
// Epilogue: 4 bands x 16 rows through 32KB EX (reused LDS).
// ---------------------------------------------------------------------------
__global__ __launch_bounds__(512, 4) void k_gru_mfma(
        const unsigned short* __restrict__ X,
        unsigned short* __restrict__ Xh,
        const unsigned short* __restrict__ Y,
        unsigned short* __restrict__ Yw,
        const unsigned short* __restrict__ Bf,
        const float* __restrict__ bbig, const float* __restrict__ Bdeg,
        const int4* __restrict__ degp) {
    __shared__ char lds[32768];     // A half-tile: 32 frags x 1KB; reused as EX

    const int tid = threadIdx.x;
    const int lane = tid & 63;
    const int wv = tid >> 6;        // 0..7 = N slot (64 cols each)
    const int r31 = lane & 31;
    const int kg = lane >> 5;
    const long row0 = (long)blockIdx.x * 64;

    f32x16 acc[2][2];               // [mt (32-row half)][ct (32-col half)]
#pragma unroll
    for (int i = 0; i < 2; i++)
#pragma unroll
        for (int j = 0; j < 2; j++) acc[i][j] = (f32x16)(0.0f);

    // A staging: frag f = k16l*2 + mt; LDS[f*1024 + lane*16] holds
    // A[row = mt*32 + (l&31)][k = k16*16 + (l>>5)*8 ..+8]. Per half: 32 frags,
    // wave wv stages f = wv*4 + jj (jj 0..3). Global src is per-lane scatter.
    const char* pAl = (const char*)X + (row0 + r31) * 1024 + kg * 16;
#define STAGE_A(HALF)                                                           \
    {                                                                           \
        _Pragma("unroll")                                                       \
        for (int jj = 0; jj < 4; jj++) {                                        \
            const int f = wv * 4 + jj;                                          \
            gload16(pAl + (f & 1) * 32768 + ((HALF) * 16 + (f >> 1)) * 32,      \
                    lds + f * 1024);                                            \
        }                                                                       \
    }

    // B fragment base pointers (ushort units), coalesced 16B/lane.
    // Wave wv owns nb = wv*2, wv*2+1 (cols wv*64 .. wv*64+63).
    const unsigned short* pB0 = Bf + (wv * 2 + 0) * 16384 + lane * 8;
    const unsigned short* pB1 = Bf + (wv * 2 + 1) * 16384 + lane * 8;

    STAGE_A(0);
    __syncthreads();

#pragma unroll
    for (int k16l = 0; k16l < 16; k16l++) {
        short8 a0 = *(const short8*)(lds + (k16l * 2 + 0) * 1024 + lane * 16);
        short8 a1 = *(const short8*)(lds + (k16l * 2 + 1) * 1024 + lane * 16);
        short8 b0 = *(const short8*)(pB0 + k16l * 512);
        short8 b1 = *(const short8*)(pB1 + k16l * 512);
        acc[0][0] = __builtin_amdgcn_mfma_f32_32x32x16_bf16(
            __builtin_bit_cast(bf16x8, a0), __builtin_bit_cast(bf16x8, b0), acc[0][0], 0, 0, 0);
        acc[0][1] = __builtin_amdgcn_mfma_f32_32x32x16_bf16(
            __builtin_bit_cast(bf16x8, a0), __builtin_bit_cast(bf16x8, b1), acc[0][1], 0, 0, 0);
        acc[1][0] = __builtin_amdgcn_mfma_f32_32x32x16_bf16(
            __builtin_bit_cast(bf16x8, a1), __builtin_bit_cast(bf16x8, b0), acc[1][0], 0, 0, 0);
        acc[1][1] = __builtin_amdgcn_mfma_f32_32x32x16_bf16(
            __builtin_bit_cast(bf16x8, a1), __builtin_bit_cast(bf16x8, b1), acc[1][1], 0, 0, 0);
    }

    __syncthreads();
    STAGE_A(1);
    __syncthreads();

#pragma unroll
    for (int k16l = 0; k16l < 16; k16l++) {
        const int k16g = 16 + k16l;
        short8 a0 = *(const short8*)(lds + (k16l * 2 + 0) * 1024 + lane * 16);
        short8 a1 = *(const short8*)(lds + (k16l * 2 + 1) * 1024 + lane * 16);
        short8 b0 = *(const short8*)(pB0 + k16g * 512);
        short8 b1 = *(const short8*)(pB1 + k16g * 512);
        acc[0][0] = __builtin_amdgcn_mfma_f32_32x32x16_bf16(
            __builtin_bit_cast(bf16x8, a0), __builtin_bit_cast(bf16x8, b0), acc[0][0], 0, 0, 0);
        acc[0][1] = __builtin_amdgcn_mfma_f32_32x32x16_bf16(
            __builtin_bit_cast(bf16x8, a0), __builtin_bit_cast(bf16x8, b1), acc[0][1], 0, 0, 0);
        acc[1][0] = __builtin_amdgcn_mfma_f32_32x32x16_bf16(
            __builtin_bit_cast(bf16x8, a1), __builtin_bit_cast(bf16x8, b0), acc[1][0], 0, 0, 0);
        acc[1][1] = __builtin_amdgcn_mfma_f32_32x32x16_bf16(
            __builtin_bit_cast(bf16x8, a1), __builtin_bit_cast(bf16x8, b1), acc[1][1], 0, 0, 0);
    }

    // ---- epilogue: 4 bands of 16 rows; EX = [16][512] f32 = 32KB ----
    float* EX = (float*)lds;
    const int ch = tid & 127;               // channel 0..127
    const int rbase = tid >> 7;             // 0..3
    const float4 bb = *(const float4*)(bbig + ch * 4);
    const float4 e0 = *(const float4*)(Bdeg + ch * 4);
    const float4 e1 = *(const float4*)(Bdeg + 512 + ch * 4);
    const float4 e2 = *(const float4*)(Bdeg + 1024 + ch * 4);

#pragma unroll
    for (int b = 0; b < 4; b++) {
        __syncthreads();
        {
            const int mt = b >> 1;
            const int qh = (b & 1) * 8;
#pragma unroll
            for (int ct = 0; ct < 2; ct++) {
                int col = wv * 64 + ct * 32 + r31;
#pragma unroll
                for (int qq = 0; qq < 8; qq++) {
                    int rwl = (qq & 3) + 8 * (qq >> 2) + 4 * kg;   // 0..15
                    EX[rwl * 512 + col] = acc[mt][ct][qh + qq];
                }
            }
        }
        __syncthreads();
#pragma unroll
        for (int i = 0; i < 4; i++) {
            int rwl = rbase + 4 * i;        // 0..15
            long grow = row0 + b * 16 + rwl;
            int4 dg = degp[grow];
            float dgx = (float)dg.x, dgy = (float)dg.y, dgz = (float)dg.z;
            float4 v = *(const float4*)(EX + rwl * 512 + ch * 4);
            float Sr = v.x + bb.x + dgx * e0.x + dgy * e1.x + dgz * e2.x;
            float Sz = v.y + bb.y + dgx * e0.y + dgy * e1.y + dgz * e2.y;
            float In = v.z + bb.z + dgx * e0.z + dgy * e1.z + dgz * e2.z;
            float Hn = v.w + bb.w;          // sec3 deg-bias is 0 by construction
            float rr = sigm(Sr);
            float zz = sigm(Sz);
            float tt = In + rr * Hn;
            float ee = __expf(2.f * tt);
            float nn = 1.f - 2.f / (ee + 1.f);
            float hv = (1.f - zz) * nn + zz * bf2f(Y[grow * HID + ch]);
            unsigned short hb = f2bf(hv);
            Yw[grow * HID + ch] = hb;
            Xh[grow * XS + 384 + ch] = hb;
        }
    }
}

// ---------------------------------------------------------------------------
// Readout: out[g] += sigmoid(h@Wg.T+bg) * (h@Wp.T+bp). h from Y bf16.
// ---------------------------------------------------------------------------
__global__ __launch_bounds__(256) void k_readout(const unsigned short* __restrict__ Y,
                                                 const int* __restrict__ n2g,
                                                 const float* __restrict__ Wp,
                                                 const float* __restrict__ bp,
                                                 const float* __restrict__ Wg,
                                                 const float* __restrict__ bg,
                                                 float* __restrict__ out) {
    __shared__ float hs[32][132];
    __shared__ float Ws[64][129];
    int tid = threadIdx.x;
    long row0 = (long)blockIdx.x * 32;
    int rg = tid >> 5, cg = tid & 31;
    float acc[4][4];
#pragma unroll
    for (int r = 0; r < 4; r++)
#pragma unroll
        for (int c = 0; c < 4; c++) acc[r][c] = 0.f;

#pragma unroll
    for (int p = 0; p < 2; p++) {
        int e = p * 256 + tid;
        int r = e >> 4, c8 = e & 15;
        short8 v = *(const short8*)(Y + (row0 + r) * HID + c8 * 8);
#pragma unroll
        for (int j = 0; j < 8; j++) hs[r][c8 * 8 + j] = bf2f((unsigned short)v[j]);
    }
    for (int kc = 0; kc < 128; kc += 64) {
        __syncthreads();
#pragma unroll
        for (int p = 0; p < 8; p++) {
            int idx = p * 256 + tid;
            int j = idx >> 4, q = idx & 15;
            const float* Wsrc = (j < 64) ? Wp : Wg;
            float4 w = *(const float4*)&Wsrc[(j & 63) * HID + kc + q * 4];
            Ws[q * 4 + 0][j] = w.x;
            Ws[q * 4 + 1][j] = w.y;
            Ws[q * 4 + 2][j] = w.z;
            Ws[q * 4 + 3][j] = w.w;
        }
        __syncthreads();
#pragma unroll 8
        for (int k = 0; k < 64; k++) {
            float a[4], w[4];
#pragma unroll
            for (int r = 0; r < 4; r++) a[r] = hs[rg * 4 + r][kc + k];
#pragma unroll
            for (int c = 0; c < 4; c++) w[c] = Ws[k][cg + 32 * c];
#pragma unroll
            for (int r = 0; r < 4; r++)
#pragma unroll
                for (int c = 0; c < 4; c++) acc[r][c] += a[r] * w[c];
        }
    }
#pragma unroll
    for (int r = 0; r < 4; r++) {
        long row = row0 + rg * 4 + r;
        if (row < NN) {
            int g = n2g[row];
            float pv0 = acc[r][0] + bp[cg];
            float pv1 = acc[r][1] + bp[cg + 32];
            float gv0 = acc[r][2] + bg[cg];
            float gv1 = acc[r][3] + bg[cg + 32];
            atomicAdd(&out[g * EMB + cg],      pv0 * sigm(gv0));
            atomicAdd(&out[g * EMB + cg + 32], pv1 * sigm(gv1));
        }
    }
}

// ---------------------------------------------------------------------------
extern "C" void kernel_launch(void* const* d_in, const int* in_sizes, int n_in,
                              void* d_out, int out_size, void* d_ws, size_t ws_size,
                              hipStream_t stream) {
    const float* node_features = (const float*)d_in[0];
    const int*   edge_index    = (const int*)d_in[1];
    const int*   n2g           = (const int*)d_in[2];
    const float* W_msg         = (const float*)d_in[3];
    const float* b_msg         = (const float*)d_in[4];
    const float* W_ih          = (const float*)d_in[5];
    const float* W_hh          = (const float*)d_in[6];
    const float* b_ih          = (const float*)d_in[7];
    const float* b_hh          = (const float*)d_in[8];
    const float* W_proj        = (const float*)d_in[9];
    const float* b_proj        = (const float*)d_in[10];
    const float* W_gate        = (const float*)d_in[11];
    const float* b_gate        = (const float*)d_in[12];

    char* ws = (char*)d_ws;
    unsigned short* X    = (unsigned short*)(ws);                 // 102,498,304 B
    unsigned short* Y    = (unsigned short*)(ws + 102498304);     //  25,624,576 B
    unsigned short* Bf   = (unsigned short*)(ws + 128122880);     //     524,288 B
    float*          bbig = (float*)         (ws + 128647168);     //       2,048 B
    float*          Bdeg = (float*)         (ws + 128649216);     //       6,144 B
    int4*           degp = (int4*)          (ws + 128655360);     //   1,601,536 B
    int*            deg  = (int*)           (ws + 130256896);     //   1,200,000 B
    int*            csr  = (int*)           (ws + 131456896);     //  38,400,000 B -> 169,856,896

    float* out = (float*)d_out;

    hipMemsetAsync(out, 0, (size_t)NG * EMB * sizeof(float), stream);
    hipMemsetAsync(deg, 0, (size_t)3 * NN * sizeof(int), stream);

    k_init<<<dim3((NNP * HID) / 256), dim3(256), 0, stream>>>(node_features, Y, X);
    k_build_csr<<<dim3((3 * NE + 255) / 256), dim3(256), 0, stream>>>(edge_index, deg, csr);
    k_pack_deg<<<dim3(NNP / 256), dim3(256), 0, stream>>>(deg, degp);
    k_build_w<<<dim3(512), dim3(512), 0, stream>>>(W_msg, W_ih, W_hh, Bf);
    k_build_bias<<<dim3(1), dim3(512), 0, stream>>>(b_ih, b_hh, b_msg, W_ih, bbig, Bdeg);

    for (int step = 0; step < 4; step++) {
        k_agg<<<dim3(NN / 4), dim3(256), 0, stream>>>(Y, X, deg, csr);
        k_gru_mfma<<<dim3(NNP / 64), dim3(512), 0, stream>>>(X, X, Y, Y, Bf,
                                                             bbig, Bdeg, degp);
    }
    k_readout<<<dim3(NN / 32), dim3(256), 0, stream>>>(Y, n2g, W_proj, b_proj,
                                                       W_gate, b_gate, out);
}